// Round 3
// baseline (56239.539 us; speedup 1.0000x reference)
//
#include <hip/hip_runtime.h>
#include <stdint.h>

// DiffusionModel: 1000 sequential forward noise+clip steps + 1 reverse step.
// JAX *partitionable* threefry semantics (default since JAX 0.4.36):
//   split(key,n):  child_t = threefry2x32(key, (0, t)); child = (o0, o1)
//   random_bits32: bits[i] = o0 ^ o1 of threefry2x32(key, (0, i))   (XOR-fold)
//   fold_in:       threefry2x32(key, (0, data))
// XLA ErfInv32: w = -log1p(-x*x), log1p as u=1+m; u==1 ? m : m*log(u)/(u-1),
// fp contract OFF in that region (reference rounds x*x and 1+m separately).
//
// R3 change vs R2 (bit-identical math): 8 elements/thread, fully unrolled.
// R2 showed VGPR_Count=12 -> compiler re-materialized every literal constant
// inside the 1000-step loop; amortize constants/branches/key-load over 8
// independent chains instead of 2. Keys moved to SGPRs via readfirstlane.

#define NTOTAL 25165824u
#define EPT    8u
#define NTHREADS (NTOTAL / EPT)   // 3,145,728 threads = 12288 blocks x 256
#define TS     1000

__device__ __forceinline__ void tf2x32(uint32_t k0, uint32_t k1,
                                       uint32_t x0, uint32_t x1,
                                       uint32_t& o0, uint32_t& o1) {
  const uint32_t k2 = k0 ^ k1 ^ 0x1BD11BDAu;
  x0 += k0; x1 += k1;
#define RR(r) { x0 += x1; x1 = (x1 << (r)) | (x1 >> (32 - (r))); x1 ^= x0; }
  RR(13) RR(15) RR(26) RR(6)
  x0 += k1; x1 += k2 + 1u;
  RR(17) RR(29) RR(16) RR(24)
  x0 += k2; x1 += k0 + 2u;
  RR(13) RR(15) RR(26) RR(6)
  x0 += k0; x1 += k1 + 3u;
  RR(17) RR(29) RR(16) RR(24)
  x0 += k1; x1 += k2 + 4u;
  RR(13) RR(15) RR(26) RR(6)
  x0 += k2; x1 += k0 + 5u;
#undef RR
  o0 = x0; o1 = x1;
}

// partitionable random_bits(32): counter (0, i), XOR-fold the two outputs.
__device__ __forceinline__ uint32_t tf_bits(uint32_t k0, uint32_t k1, uint32_t i) {
  uint32_t o0, o1;
  tf2x32(k0, k1, 0u, i, o0, o1);
  return o0 ^ o1;
}

// jax _uniform(lo=nextafter(-1,0)=-0.99999994, hi=1): bits>>9 | 1.0f, bitcast,
// -1, then f*(hi-lo)+lo with (hi-lo) == 2.0f exactly in f32.
__device__ __forceinline__ float bits_to_u(uint32_t b) {
  float f = __uint_as_float((b >> 9) | 0x3f800000u) - 1.0f;
  float u = fmaf(f, 2.0f, -0.99999994f);
  return fmaxf(-0.99999994f, u);
}

// XLA ErfInv32 (Giles). Tail branch |x| > ~0.9966 (p ~ 0.34%/draw).
__device__ __forceinline__ float erfinv_f(float x) {
#pragma clang fp contract(off)
  float t = x * x;
  float m = -t;
  float u = m + 1.0f;
  float lg;
  if (u == 1.0f) {
    lg = m;
  } else {
    lg = m * __fdividef(__logf(u), u - 1.0f);
  }
  float w = -lg;
  float p;
  if (w < 5.0f) {
    w = w - 2.5f;
    p = 2.81022636e-08f;
    p = fmaf(p, w, 3.43273939e-07f);
    p = fmaf(p, w, -3.5233877e-06f);
    p = fmaf(p, w, -4.39150654e-06f);
    p = fmaf(p, w, 0.00021858087f);
    p = fmaf(p, w, -0.00125372503f);
    p = fmaf(p, w, -0.00417768164f);
    p = fmaf(p, w, 0.246640727f);
    p = fmaf(p, w, 1.50140941f);
  } else {
    w = sqrtf(w) - 3.0f;
    p = -0.000200214257f;
    p = fmaf(p, w, 0.000100950558f);
    p = fmaf(p, w, 0.00134934322f);
    p = fmaf(p, w, -0.00367342844f);
    p = fmaf(p, w, 0.00573950773f);
    p = fmaf(p, w, -0.0076224613f);
    p = fmaf(p, w, 0.00943887047f);
    p = fmaf(p, w, 1.00167406f);
    p = fmaf(p, w, 2.83297682f);
  }
  return p * x;
}

// noise = 0.1f * (sqrt2_f32 * erfinv(u)) — two separate muls (JAX rounding).
__device__ __forceinline__ float noise_from_bits(uint32_t b) {
  return 0.1f * (1.41421356f * erfinv_f(bits_to_u(b)));
}

__global__ __launch_bounds__(256) void diffusion_kernel(
    const float* __restrict__ x, float* __restrict__ out) {
  // Step keys (partitionable split): key_t = threefry((0,1), (0,t)).
  // Recomputed per block into LDS (~4 calls/thread preamble).
  __shared__ alignas(16) uint32_t skeys[2 * TS];
  const int tid = threadIdx.x;
  for (int j = tid; j < TS; j += 256) {
    uint32_t o0, o1;
    tf2x32(0u, 1u, 0u, (uint32_t)j, o0, o1);
    skeys[2 * j] = o0;
    skeys[2 * j + 1] = o1;
  }
  __syncthreads();

  const uint32_t i = blockIdx.x * 256u + (uint32_t)tid;  // exact grid, no bounds check
  const uint32_t base = i * EPT;

  float4 v0 = ((const float4*)x)[2 * i];
  float4 v1 = ((const float4*)x)[2 * i + 1];
  float xv[EPT] = {v0.x, v0.y, v0.z, v0.w, v1.x, v1.y, v1.z, v1.w};

  for (int t = 0; t < TS; ++t) {
    // wave-uniform key -> SGPRs (all lanes read same LDS addr; all lanes active)
    const uint32_t k0 = (uint32_t)__builtin_amdgcn_readfirstlane((int)skeys[2 * t]);
    const uint32_t k1 = (uint32_t)__builtin_amdgcn_readfirstlane((int)skeys[2 * t + 1]);
    uint32_t b[EPT];
#pragma unroll
    for (uint32_t e = 0; e < EPT; ++e) b[e] = tf_bits(k0, k1, base + e);
#pragma unroll
    for (uint32_t e = 0; e < EPT; ++e) {
      xv[e] = fminf(1.0f, fmaxf(0.0f, xv[e] + noise_from_bits(b[e])));
    }
  }

  // rev_key = fold_in(key(2), 999) = threefry((0,2),(0,999)) — constant-folded.
  uint32_t rk0, rk1;
  tf2x32(0u, 2u, 0u, 999u, rk0, rk1);
  float ov[EPT];
#pragma unroll
  for (uint32_t e = 0; e < EPT; ++e) {
    float r = noise_from_bits(tf_bits(rk0, rk1, base + e));
    ov[e] = fminf(1.0f, fmaxf(0.0f, xv[e] - r));
  }
  float4 s0 = {ov[0], ov[1], ov[2], ov[3]};
  float4 s1 = {ov[4], ov[5], ov[6], ov[7]};
  ((float4*)out)[2 * i] = s0;
  ((float4*)out)[2 * i + 1] = s1;
}

extern "C" void kernel_launch(void* const* d_in, const int* in_sizes, int n_in,
                              void* d_out, int out_size, void* d_ws, size_t ws_size,
                              hipStream_t stream) {
  (void)in_sizes; (void)n_in; (void)d_ws; (void)ws_size; (void)out_size;
  const float* x = (const float*)d_in[0];
  float* out = (float*)d_out;
  dim3 block(256);
  dim3 grid(NTHREADS / 256);  // 12288 blocks
  hipLaunchKernelGGL(diffusion_kernel, grid, block, 0, stream, x, out);
}

// Round 4
// 52025.970 us; speedup vs baseline: 1.0810x; 1.0810x over previous
//
#include <hip/hip_runtime.h>
#include <stdint.h>

// DiffusionModel: 1000 sequential forward noise+clip steps + 1 reverse step.
// JAX *partitionable* threefry semantics (default since JAX 0.4.36):
//   split(key,n):  child_t = threefry2x32(key, (0, t)); child = (o0, o1)
//   random_bits32: bits[i] = o0 ^ o1 of threefry2x32(key, (0, i))   (XOR-fold)
//   fold_in:       threefry2x32(key, (0, data))
//
// R4 vs R3: minimize VALU issue-slots (we are issue-bound, not latency-bound):
//  - rotl forced to v_alignbit_b32 (1 instr) via __builtin_amdgcn_alignbit
//  - erfinv: XLA's log1p emulation m*log(u)/(u-1) replaced by plain -log(u).
//    Proof of safety: correction differs from 1 by <= ulp(1)/|u-1| => |dw| <=
//    2^-24 absolute; poly is smooth in w => noise error < 1e-7/draw. Kills
//    v_rcp + select + 2 muls. (u = 1 - x*x kept as two ref-identical
//    roundings: fma here is NOT safe — up to 50% rel change in tail u.)
//  - redundant fmax(lo, u) dropped (fma result >= lo provably)
//  - 0.1*(sqrt2*t) fused to one constant mul (<=1 ulp)
//  - clip via v_med3_f32 (identical for finite inputs)
//  - EPT=4 (R2's EPT2 > R3's EPT8; middle + float4 I/O), key prefetch t+1

#define NTOTAL 25165824u
#define EPT    4u
#define NTHREADS (NTOTAL / EPT)   // 6,291,456 threads = 24576 blocks x 256
#define TS     1000

__device__ __forceinline__ uint32_t rotl32(uint32_t x, int r) {
  // alignbit(a,b,c) = (a:b) >> c  =>  alignbit(x,x,32-r) = rotl(x,r)
  return __builtin_amdgcn_alignbit(x, x, 32 - r);
}

__device__ __forceinline__ void tf2x32(uint32_t k0, uint32_t k1,
                                       uint32_t x0, uint32_t x1,
                                       uint32_t& o0, uint32_t& o1) {
  const uint32_t k2 = k0 ^ k1 ^ 0x1BD11BDAu;
  x0 += k0; x1 += k1;
#define RR(r) { x0 += x1; x1 = rotl32(x1, r); x1 ^= x0; }
  RR(13) RR(15) RR(26) RR(6)
  x0 += k1; x1 += k2 + 1u;
  RR(17) RR(29) RR(16) RR(24)
  x0 += k2; x1 += k0 + 2u;
  RR(13) RR(15) RR(26) RR(6)
  x0 += k0; x1 += k1 + 3u;
  RR(17) RR(29) RR(16) RR(24)
  x0 += k1; x1 += k2 + 4u;
  RR(13) RR(15) RR(26) RR(6)
  x0 += k2; x1 += k0 + 5u;
#undef RR
  o0 = x0; o1 = x1;
}

// partitionable random_bits(32): counter (0, i), XOR-fold the two outputs.
__device__ __forceinline__ uint32_t tf_bits(uint32_t k0, uint32_t k1, uint32_t i) {
  uint32_t o0, o1;
  tf2x32(k0, k1, 0u, i, o0, o1);
  return o0 ^ o1;
}

// bits -> u in (-1,1): (b>>9)|1.0f, -1, fma(f,2,lo). fmax(lo,.) is a no-op
// (f >= 0), dropped.
__device__ __forceinline__ float bits_to_u(uint32_t b) {
  float f = __uint_as_float((b >> 9) | 0x3f800000u) - 1.0f;
  return fmaf(f, 2.0f, -0.99999994f);
}

// XLA ErfInv32 (Giles), with -log1p(-x*x) -> -log(1 - x*x) (|dw|<=2^-24, safe).
__device__ __forceinline__ float erfinv_f(float x) {
#pragma clang fp contract(off)
  float t = x * x;
  float u = 1.0f - t;     // two roundings, ref-identical; do NOT fma
  float w = -__logf(u);   // u >= 1.19e-7 always; w in [0, ~15.9]
  float p;
  if (__builtin_expect(!(w < 5.0f), 0)) {
    float s = sqrtf(w) - 3.0f;
    p = -0.000200214257f;
    p = fmaf(p, s, 0.000100950558f);
    p = fmaf(p, s, 0.00134934322f);
    p = fmaf(p, s, -0.00367342844f);
    p = fmaf(p, s, 0.00573950773f);
    p = fmaf(p, s, -0.0076224613f);
    p = fmaf(p, s, 0.00943887047f);
    p = fmaf(p, s, 1.00167406f);
    p = fmaf(p, s, 2.83297682f);
  } else {
    float s = w - 2.5f;
    p = 2.81022636e-08f;
    p = fmaf(p, s, 3.43273939e-07f);
    p = fmaf(p, s, -3.5233877e-06f);
    p = fmaf(p, s, -4.39150654e-06f);
    p = fmaf(p, s, 0.00021858087f);
    p = fmaf(p, s, -0.00125372503f);
    p = fmaf(p, s, -0.00417768164f);
    p = fmaf(p, s, 0.246640727f);
    p = fmaf(p, s, 1.50140941f);
  }
  return p * x;
}

// noise = (0.1*sqrt2) * erfinv(u) — fused constant, <=1 ulp vs two muls.
__device__ __forceinline__ float noise_from_bits(uint32_t b) {
  const float c = 0.1f * 1.41421356f;  // host-folded, single rounding
  return c * erfinv_f(bits_to_u(b));
}

__device__ __forceinline__ float clamp01(float v) {
  return __builtin_amdgcn_fmed3f(v, 0.0f, 1.0f);  // == min(1,max(0,v)) finite
}

__global__ __launch_bounds__(256) void diffusion_kernel(
    const float* __restrict__ x, float* __restrict__ out) {
  // Step keys (partitionable split): key_t = threefry((0,1), (0,t)).
  // +1 pad slot so the t+1 prefetch never reads OOB.
  __shared__ alignas(16) uint2 skeys[TS + 1];
  const int tid = threadIdx.x;
  for (int j = tid; j < TS + 1; j += 256) {
    uint32_t o0, o1;
    tf2x32(0u, 1u, 0u, (uint32_t)(j < TS ? j : 0), o0, o1);
    skeys[j] = make_uint2(o0, o1);
  }
  __syncthreads();

  const uint32_t i = blockIdx.x * 256u + (uint32_t)tid;  // exact grid
  const uint32_t base = i * EPT;

  float4 xv = ((const float4*)x)[i];
  float v[EPT] = {xv.x, xv.y, xv.z, xv.w};

  uint2 kcur = skeys[0];
  for (int t = 0; t < TS; ++t) {
    const uint32_t k0 = (uint32_t)__builtin_amdgcn_readfirstlane((int)kcur.x);
    const uint32_t k1 = (uint32_t)__builtin_amdgcn_readfirstlane((int)kcur.y);
    kcur = skeys[t + 1];  // prefetch next key; waitcnt lands far from use
    uint32_t b[EPT];
#pragma unroll
    for (uint32_t e = 0; e < EPT; ++e) b[e] = tf_bits(k0, k1, base + e);
#pragma unroll
    for (uint32_t e = 0; e < EPT; ++e) {
      v[e] = clamp01(v[e] + noise_from_bits(b[e]));
    }
  }

  // rev_key = fold_in(key(2), 999) = threefry((0,2),(0,999)) — constant-folded.
  uint32_t rk0, rk1;
  tf2x32(0u, 2u, 0u, 999u, rk0, rk1);
  float4 ov;
  float* op = &ov.x;
#pragma unroll
  for (uint32_t e = 0; e < EPT; ++e) {
    float r = noise_from_bits(tf_bits(rk0, rk1, base + e));
    op[e] = clamp01(v[e] - r);
  }
  ((float4*)out)[i] = ov;
}

extern "C" void kernel_launch(void* const* d_in, const int* in_sizes, int n_in,
                              void* d_out, int out_size, void* d_ws, size_t ws_size,
                              hipStream_t stream) {
  (void)in_sizes; (void)n_in; (void)d_ws; (void)ws_size; (void)out_size;
  const float* x = (const float*)d_in[0];
  float* out = (float*)d_out;
  dim3 block(256);
  dim3 grid(NTHREADS / 256);  // 24576 blocks
  hipLaunchKernelGGL(diffusion_kernel, grid, block, 0, stream, x, out);
}